// Round 5
// baseline (313.513 us; speedup 1.0000x reference)
//
#include <hip/hip_runtime.h>

// ---------------------------------------------------------------------------
// Kernel 0: replicate the reference's fp32 cas table EXACTLY:
//   ang  = fp32( fp32(2*pi/128) * fp32(f*m) )   (UNREDUCED angle, up to ~792)
//   cas  = fp32(cos(ang)) + fp32(sin(ang))      (per-term fp32 rounding)
// Must match the reference's table (a more accurate table FAILS: cosphi =
// C/hypot amplifies table mismatch at small-hypot pixels).
// ---------------------------------------------------------------------------
__global__ void k_cas(float* __restrict__ casf) {
    int f = blockIdx.x, m = threadIdx.x;
    const float SC = (float)(6.283185307179586 / 128.0);  // fp32(2*pi/128)
    float ang = SC * (float)(f * m);                      // fp32 multiply, unreduced
    double a = (double)ang;
    float cv = (float)cos(a);
    float sv = (float)sin(a);
    casf[f * 128 + m] = cv + sv;                          // fp32 add
}

// ---------------------------------------------------------------------------
// Kernel 1: per (image, g-quarter): C = cas*X*cas, S = cas*Xf*cas restricted
// to 32 spectral columns G0..G0+31.
//   Phase 1: T1[m,g] = sum_k X[m,k] cas[k,g]        (row transform)
//            T2[127-m,g] = sum_k X[m,k] cas[127-k,g] (flipped-image rows)
//     using k/(127-k) pairing so each casQ read feeds both T1 and T2.
//   Phase 2: C[f,g] = sum_m cas[f,m] T1[m,g];  S likewise from T2.
//   cosphi = C*rsqrt(C^2+S^2) -> d_out (scratch); corners of C -> cp1/cp2.
// LDS 48KB (casQ 16K + T1 16K + T2 16K) -> 3 blocks/CU, 12 waves/CU.
// 256 thr: rowg=t>>3 (4 rows), colg=t&7 (4 cols). X and cas f-rows from L1.
// ---------------------------------------------------------------------------
__global__ __launch_bounds__(256) void k_dht(
    const float* __restrict__ xg,
    const float* __restrict__ cas,
    float* __restrict__ cosphi,
    float* __restrict__ cp1,
    float* __restrict__ cp2)
{
    __shared__ float casQ[128 * 32];   // casQ[k][j] = cas[k][G0+j]
    __shared__ float T1s[128 * 32];
    __shared__ float T2s[128 * 32];

    const int img = blockIdx.x;
    const int G0  = blockIdx.y * 32;
    const float* X = xg + (size_t)img * 16384;
    const int t = threadIdx.x;

    // stage the 32-column cas slice (coalesced: 32 consecutive t = one row seg)
    #pragma unroll
    for (int r = 0; r < 16; ++r) {
        int idx = t + r * 256;             // 0..4095
        int k = idx >> 5, j = idx & 31;
        casQ[idx] = cas[k * 128 + G0 + j];
    }
    __syncthreads();

    const int rowg = t >> 3;               // 0..31
    const int colg = t & 7;                // 0..7
    const int r0 = rowg * 4;               // 4 rows per thread
    const int j0 = colg * 4;               // 4 cols per thread

    // ---- phase 1 ----
    float R1[4][4], R2[4][4];
    #pragma unroll
    for (int i = 0; i < 4; ++i)
        #pragma unroll
        for (int l = 0; l < 4; ++l) { R1[i][l] = 0.f; R2[i][l] = 0.f; }

    for (int kk = 0; kk < 64; kk += 4) {
        float4 Xa[4], Xb[4];
        #pragma unroll
        for (int i = 0; i < 4; ++i) {
            Xa[i] = *(const float4*)&X[(r0 + i) * 128 + kk];          // cols kk..kk+3
            Xb[i] = *(const float4*)&X[(r0 + i) * 128 + 124 - kk];    // cols 124-kk..127-kk
        }
        #pragma unroll
        for (int u = 0; u < 4; ++u) {
            const int k = kk + u;
            float4 c1 = *(const float4*)&casQ[k * 32 + j0];           // cas[k][g]
            float4 c2 = *(const float4*)&casQ[(127 - k) * 32 + j0];   // cas[127-k][g]
            #pragma unroll
            for (int i = 0; i < 4; ++i) {
                float x1 = ((const float*)&Xa[i])[u];                 // X[r][k]
                float x2 = ((const float*)&Xb[i])[3 - u];             // X[r][127-k]
                #pragma unroll
                for (int l = 0; l < 4; ++l) {
                    float c1l = ((const float*)&c1)[l];
                    float c2l = ((const float*)&c2)[l];
                    R1[i][l] = fmaf(x1, c1l, R1[i][l]);
                    R1[i][l] = fmaf(x2, c2l, R1[i][l]);
                    R2[i][l] = fmaf(x1, c2l, R2[i][l]);
                    R2[i][l] = fmaf(x2, c1l, R2[i][l]);
                }
            }
        }
    }
    #pragma unroll
    for (int i = 0; i < 4; ++i) {
        float4 v1 = { R1[i][0], R1[i][1], R1[i][2], R1[i][3] };
        float4 v2 = { R2[i][0], R2[i][1], R2[i][2], R2[i][3] };
        *(float4*)&T1s[(r0 + i) * 32 + j0]       = v1;   // T1 row r
        *(float4*)&T2s[(127 - r0 - i) * 32 + j0] = v2;   // T2 row 127-r
    }
    __syncthreads();

    // ---- phase 2 ----
    const int f0 = rowg * 4;               // 4 f-rows per thread
    float C[4][4], S[4][4];
    #pragma unroll
    for (int i = 0; i < 4; ++i)
        #pragma unroll
        for (int l = 0; l < 4; ++l) { C[i][l] = 0.f; S[i][l] = 0.f; }

    for (int mm = 0; mm < 128; mm += 4) {
        float4 a[4];
        #pragma unroll
        for (int i = 0; i < 4; ++i)
            a[i] = *(const float4*)&cas[(f0 + i) * 128 + mm];         // cas[f][m..m+3]
        #pragma unroll
        for (int u = 0; u < 4; ++u) {
            const int m = mm + u;
            float4 t1 = *(const float4*)&T1s[m * 32 + j0];
            float4 t2 = *(const float4*)&T2s[m * 32 + j0];
            #pragma unroll
            for (int i = 0; i < 4; ++i) {
                float av = ((const float*)&a[i])[u];
                #pragma unroll
                for (int l = 0; l < 4; ++l) {
                    C[i][l] = fmaf(av, ((const float*)&t1)[l], C[i][l]);
                    S[i][l] = fmaf(av, ((const float*)&t2)[l], S[i][l]);
                }
            }
        }
    }

    // ---- epilogue: cosphi + corner extraction ----
    const size_t base = (size_t)img * 16384;
    #pragma unroll
    for (int i = 0; i < 4; ++i) {
        const int f = f0 + i;
        float4 o;
        #pragma unroll
        for (int l = 0; l < 4; ++l) {
            float Cv = C[i][l], Sv = S[i][l];
            float d = Cv * Cv + Sv * Sv;
            ((float*)&o)[l] = (d > 0.f) ? Cv * rsqrtf(d) : 1.0f;
        }
        *(float4*)&cosphi[base + f * 128 + G0 + j0] = o;
        if (G0 == 0 && j0 < 16) {
            if (f < 16) {
                #pragma unroll
                for (int l = 0; l < 4; ++l)
                    cp1[img * 256 + f * 16 + j0 + l] = C[i][l];
            } else if (f >= 112) {
                #pragma unroll
                for (int l = 0; l < 4; ++l)
                    cp2[img * 256 + (f - 112) * 16 + j0 + l] = C[i][l];
            }
        }
    }
}

// ---------------------------------------------------------------------------
// Kernel 2: corner complex-mul.
// od[b,o,x,y] = 0.5 * sum_i ( A*(W+Wn) + An*(W-Wn) )
// ---------------------------------------------------------------------------
__global__ __launch_bounds__(256) void k_corner(
    const float* __restrict__ cp1, const float* __restrict__ cp2,
    const float* __restrict__ w1,  const float* __restrict__ w2,
    float* __restrict__ od1, float* __restrict__ od2)
{
    const int c = blockIdx.y;
    const float* cp = c ? cp2 : cp1;
    const float* w  = c ? w2  : w1;
    float* od       = c ? od2 : od1;
    const int b = blockIdx.x >> 6, o = blockIdx.x & 63;
    const int t = threadIdx.x;
    const int xx = t >> 4, yy = t & 15;
    const int nx = (16 - xx) & 15, ny = (16 - yy) & 15;

    float acc = 0.f;
    #pragma unroll 4
    for (int i = 0; i < 64; ++i) {
        float A  = cp[((b * 64 + i) * 16 + xx) * 16 + yy];
        float An = cp[((b * 64 + i) * 16 + nx) * 16 + ny];
        float W  = w[((i * 64 + o) * 16 + xx) * 16 + yy];
        float Wn = w[((i * 64 + o) * 16 + nx) * 16 + ny];
        acc += A * (W + Wn) + An * (W - Wn);
    }
    od[((b * 64 + o) * 16 + xx) * 16 + yy] = 0.5f * acc;
}

// ---------------------------------------------------------------------------
// Kernel 3: sparse inverse DHT + final multiply (in place on d_out).
// ---------------------------------------------------------------------------
__global__ __launch_bounds__(256) void k_inv(
    const float* __restrict__ od1, const float* __restrict__ od2,
    const float* __restrict__ cas,
    float* __restrict__ out)
{
    __shared__ float odS[32 * 16];     // rows 0..15: od1, 16..31: od2
    __shared__ float casF[128 * 33];   // casF[s][j] = cas[s][ j<16 ? j : 96+j ]
    __shared__ float Rs[128 * 17];     // padded
    __shared__ float casG[16 * 128];   // cas rows 0..15

    const int img = blockIdx.x;
    const int t = threadIdx.x;

    odS[t]       = od1[img * 256 + t];
    odS[256 + t] = od2[img * 256 + t];
    #pragma unroll
    for (int k = 0; k < 16; ++k) {
        int idx = t + k * 256;
        int s = idx >> 5, j = idx & 31;
        int f = (j < 16) ? j : (96 + j);
        casF[s * 33 + j] = cas[s * 128 + f];
    }
    #pragma unroll
    for (int k = 0; k < 8; ++k) {
        int idx = t + k * 256;
        casG[idx] = cas[idx];
    }
    __syncthreads();

    {
        const int s1 = t >> 1, gb = (t & 1) * 8;
        float acc[8];
        #pragma unroll
        for (int l = 0; l < 8; ++l) acc[l] = 0.f;
        #pragma unroll 4
        for (int j = 0; j < 32; ++j) {
            float cf = casF[s1 * 33 + j];
            #pragma unroll
            for (int l = 0; l < 8; ++l)
                acc[l] = fmaf(cf, odS[j * 16 + gb + l], acc[l]);
        }
        #pragma unroll
        for (int l = 0; l < 8; ++l) Rs[s1 * 17 + gb + l] = acc[l];
    }
    __syncthreads();

    const float inv = 1.0f / 16384.0f;
    const int grp = t >> 5, lane = t & 31;
    const int s2 = lane * 4;
    for (int r = 0; r < 16; ++r) {
        const int s1 = grp * 16 + r;
        float4 acc = {0.f, 0.f, 0.f, 0.f};
        #pragma unroll
        for (int g = 0; g < 16; ++g) {
            float rv = Rs[s1 * 17 + g];
            float4 c4 = *(const float4*)&casG[g * 128 + s2];
            acc.x = fmaf(rv, c4.x, acc.x);
            acc.y = fmaf(rv, c4.y, acc.y);
            acc.z = fmaf(rv, c4.z, acc.z);
            acc.w = fmaf(rv, c4.w, acc.w);
        }
        size_t idx = (size_t)img * 16384 + (size_t)s1 * 128 + s2;
        float4 ph = *(const float4*)&out[idx];
        float4 res;
        res.x = acc.x * inv * ph.x;
        res.y = acc.y * inv * ph.y;
        res.z = acc.z * inv * ph.z;
        res.w = acc.w * inv * ph.w;
        *(float4*)&out[idx] = res;
    }
}

// ---------------------------------------------------------------------------
extern "C" void kernel_launch(void* const* d_in, const int* in_sizes, int n_in,
                              void* d_out, int out_size, void* d_ws, size_t ws_size,
                              hipStream_t stream) {
    (void)in_sizes; (void)n_in; (void)out_size; (void)ws_size;
    const float* x  = (const float*)d_in[0];
    const float* w1 = (const float*)d_in[1];
    const float* w2 = (const float*)d_in[2];
    float* out = (float*)d_out;
    float* ws  = (float*)d_ws;

    float* casf = ws;                // 16384
    float* cp1  = casf + 16384;      // 262144  (16*64*16*16)
    float* cp2  = cp1 + 262144;      // 262144
    float* od1  = cp2 + 262144;      // 262144
    float* od2  = od1 + 262144;      // 262144   total ~4.3 MB

    k_cas<<<dim3(128), dim3(128), 0, stream>>>(casf);
    k_dht<<<dim3(1024, 4), dim3(256), 0, stream>>>(x, casf, out, cp1, cp2);
    k_corner<<<dim3(1024, 2), dim3(256), 0, stream>>>(cp1, cp2, w1, w2, od1, od2);
    k_inv<<<dim3(1024), dim3(256), 0, stream>>>(od1, od2, casf, out);
}